// Round 6
// baseline (5437.708 us; speedup 1.0000x reference)
//
#include <hip/hip_runtime.h>
#include <hip/hip_bf16.h>

// LSTM chain: B=256, S=512, H=256, V=128.
// Round 5 re-run (rounds 3/5 benches died on GPUAcquisitionTimeout, never ran).
// N-split across 8 CUs per chain-group + coherent h all-gather.
//
// Why: W bf16 = 512 KB = the ENTIRE per-CU register file (and 3.2x LDS), so any
// one-CU-per-group design streams 512 KB/step from L2 (~16k cyc) -> 3.5 ms floor
// (rounds 1/2/4 all measured this). Splitting the 1024 z-cols over 8 blocks makes
// the per-block W slice 8 frags/wave = 32 VGPRs -> truly register-resident.
//
// Structure: 128 blocks = 16 groups x 8. Block (g,j) owns batch rows [16g,16g+16)
// and h-cols [32j,32j+32) (z-cols {q*256+32j..+32}, q=0..3 -> 8 MFMA tiles).
// Per step: 8x ds_read_b128 A-frags (full h, frag layout) -> 8 MFMA/wave ->
// z to LDS (padded, conflict-free) -> gates fp32, c-state 1 float/thread ->
// pack h bf16 via shfl -> publish own 1 KB slice with agent-scope 8B atomic
// stores -> release flag -> 8-lane spin on the group's 8 flags + barrier as
// broadcast -> acquire fence -> gather 8 KB (all slices) with agent-scope loads
// -> rebuild A-fragment hbuf -> barrier.
// Co-residency for the spin: 83 KB LDS pad forces 1 block/CU; 128 blocks <= 256
// CUs -> all resident -> no deadlock. Flags/zx tables re-inited by prep kernel
// every launch (ws is re-poisoned between replays).
// A/B fragment k-order uses one consistent bijection k = 32s + 8*(lane>>4) + elem
// on both operands; C/D layout (HW-verified): col = lane&15, row = 4*(lane>>4)+reg.

#define HID    256
#define FOURH  1024
#define SLEN   512
#define NVOCAB 128

typedef __attribute__((ext_vector_type(8))) __bf16 bf16x8;
typedef __attribute__((ext_vector_type(4))) float  f32x4;
typedef unsigned long long ull;

__device__ __forceinline__ unsigned short f2bf(float x) {
  unsigned int u = __builtin_bit_cast(unsigned int, x);
  u = (u + 0x7FFFu + ((u >> 16) & 1u)) >> 16;   // RNE
  return (unsigned short)u;
}
__device__ __forceinline__ float sigmoid_(float x) {
  return __builtin_amdgcn_rcpf(1.f + __expf(-x));
}
__device__ __forceinline__ float tanh_(float x) {
  return 1.f - 2.f * __builtin_amdgcn_rcpf(__expf(2.f * x) + 1.f);
}

// ---------------- prep: zxs table + Wb fragment repack + flag zero ----------------
__global__ __launch_bounds__(256) void lstm_prep(
    const float* __restrict__ emb, const float* __restrict__ W,
    const float* __restrict__ b, float* __restrict__ zxs,
    unsigned short* __restrict__ Wb, unsigned int* __restrict__ flags)
{
  const int blk = blockIdx.x;
  if (blk < NVOCAB) {
    if (blk == 0 && threadIdx.x < 128) flags[threadIdx.x] = 0;  // 16 groups x 8
    // zxs[v][j][cloc][q] = emb[v] @ W[:, q*256 + j*32 + cloc] + b[...]
    __shared__ float ev[HID];
    const int v = blk;
    for (int i = threadIdx.x; i < HID; i += 256) ev[i] = emb[v * HID + i];
    __syncthreads();
    const int jj = threadIdx.x >> 5, cloc = threadIdx.x & 31;
    for (int q = 0; q < 4; ++q) {
      const int col = q * 256 + threadIdx.x;
      float acc = b[col];
      #pragma unroll 4
      for (int k = 0; k < HID; ++k)
        acc += ev[k] * W[(HID + k) * FOURH + col];   // coalesced across threads
      zxs[(((size_t)v * 8 + jj) * 32 + cloc) * 4 + q] = acc;
    }
  } else {
    // Wb frag layout: tile c, kstep s: elem (g,r,jj) at (((c*8+s)*4+g)*16+r)*8+jj
    // holds Wh[k = 32s+8g+jj][zcol = 16c+r]  (per-lane 16B fully linear).
    int idx = (blk - NVOCAB) * 256 + threadIdx.x;    // (c,s,g,r)
    const int c = idx >> 9;
    const int rem = idx & 511;
    const int s = rem >> 6, gg = (rem >> 4) & 3, r = rem & 15;
    const int col = 16 * c + r;
    #pragma unroll
    for (int j = 0; j < 8; ++j) {
      const int k = 32 * s + 8 * gg + j;
      Wb[(((c * 8 + s) * 4 + gg) * 16 + r) * 8 + j] = f2bf(W[k * FOURH + col]);
    }
  }
}

// ---------------- sequential recurrence, 8 blocks per chain group ----------------
__global__ __launch_bounds__(512, 2) void lstm_seq(
    const int* __restrict__ tokens, const float* __restrict__ zxs,
    const unsigned short* __restrict__ Wb, ull* xbuf,
    unsigned int* flags, float* __restrict__ out)
{
  // h fragments (full 16 rows x 256 k-cols, bf16): elem ((s*4+g)*16+r)*8+jj
  __shared__ __align__(16) unsigned short hbuf[4096];   // 8 KB
  __shared__ float zbuf[4][16][33];                     // 8448 B, pad 33 vs bank conflicts
  __shared__ ull lpad[8320];                            // 66.5 KB pad -> 1 block/CU

  const int tid = threadIdx.x;
  const int w = tid >> 6, l = tid & 63;
  const int q = w & 3, hc = w >> 2;            // wave's gate and 16-col half
  const int gid = blockIdx.x >> 3, j = blockIdx.x & 7;
  const int b0 = gid * 16;
  const int ctile = q * 16 + j * 2 + hc;       // global 16-col z-tile index

  if (tokens[0] == -2147483647) lpad[tid] = 0; // keep pad allocated (never true)

  // --- W slice: 8 fragments = 32 VGPRs, resident for the whole sequence ---
  bf16x8 wf[8];
  #pragma unroll
  for (int s = 0; s < 8; ++s)
    wf[s] = *reinterpret_cast<const bf16x8*>(
        Wb + (size_t)ctile * 4096 + s * 512 + l * 8);
  #pragma unroll
  for (int s = 0; s < 8; ++s) asm volatile("" : "+v"(wf[s]));

  // zero h0 fragments
  for (int i = tid; i < 1024; i += 512) reinterpret_cast<ull*>(hbuf)[i] = 0;

  const int gr = tid >> 5, gc = tid & 31;      // gates phase: row, local col
  float cst = 0.f;                             // c-state: one scalar per thread
  ull* xg = xbuf + (size_t)gid * 2048;         // group exchange: 2 slots x 8 x 128
  unsigned int* fg = flags + gid * 8;

  __syncthreads();

  // prologue: t=0 token projection
  int tok0 = tokens[(b0 + gr) * SLEN];
  f32x4 zxc = *reinterpret_cast<const f32x4*>(
      &zxs[(((size_t)tok0 * 8 + j) * 32 + gc) * 4]);

  unsigned int tgt = 1;
  #pragma unroll 1
  for (int t = 0; t < SLEN; ++t) {
    // prefetch t+1 projection (independent of recurrence)
    const int tn = (t + 1 < SLEN) ? t + 1 : SLEN - 1;
    const int tokn = tokens[(b0 + gr) * SLEN + tn];
    const f32x4 zxn = *reinterpret_cast<const f32x4*>(
        &zxs[(((size_t)tokn * 8 + j) * 32 + gc) * 4]);

    // A fragments: 8 x ds_read_b128, linear, conflict-free
    bf16x8 a[8];
    #pragma unroll
    for (int s = 0; s < 8; ++s)
      a[s] = *reinterpret_cast<const bf16x8*>(&hbuf[(s * 64 + l) * 8]);

    // one z-tile per wave, K=256
    f32x4 A = {0.f, 0.f, 0.f, 0.f};
    #pragma unroll
    for (int s = 0; s < 8; ++s)
      A = __builtin_amdgcn_mfma_f32_16x16x32_bf16(a[s], wf[s], A, 0, 0, 0);
    #pragma unroll
    for (int p = 0; p < 4; ++p)
      zbuf[q][4 * (l >> 4) + p][hc * 16 + (l & 15)] = A[p];
    __syncthreads();                                           // B1

    // gates: thread (gr, gc) owns h[gr][32j+gc]
    const float zi = zbuf[0][gr][gc] + zxc[0];
    const float zf = zbuf[1][gr][gc] + zxc[1];
    const float zo = zbuf[2][gr][gc] + zxc[2];
    const float zu = zbuf[3][gr][gc] + zxc[3];
    const float iv = sigmoid_(zi);
    const float fv = sigmoid_(zf);
    const float ov = sigmoid_(zo);
    const float uv = tanh_(zu);
    const float cn = iv * uv + fv * cst;
    cst = cn;
    const float hn = ov * tanh_(cn);
    out[(size_t)(b0 + gr) * (SLEN * HID) + (size_t)t * HID + j * 32 + gc] = hn;
    zxc = zxn;

    // pack 4 lanes' bf16 -> 8B chunk, publish own slice (agent-coherent)
    const unsigned hu = (unsigned)f2bf(hn);
    const unsigned v01 = hu | ((unsigned)__shfl_down((int)hu, 1) << 16);
    const ull vch = (ull)v01 | ((ull)(unsigned)__shfl_down((int)v01, 2) << 32);
    const int slot = t & 1;
    if ((tid & 3) == 0) {
      const int m = (tid >> 2) & 7;              // chunk within row gr
      __hip_atomic_store(&xg[(slot * 8 + j) * 128 + gr * 8 + m], vch,
                         __ATOMIC_RELAXED, __HIP_MEMORY_SCOPE_AGENT);
    }
    __syncthreads();          // B2: drains vmcnt for all publishing threads
    if (tid == 0)
      __hip_atomic_store(&fg[j], tgt, __ATOMIC_RELEASE, __HIP_MEMORY_SCOPE_AGENT);

    // 8-lane spin on the group's flags; barrier broadcasts completion
    if (tid < 8) {
      while (__hip_atomic_load(&fg[tid], __ATOMIC_RELAXED,
                               __HIP_MEMORY_SCOPE_AGENT) < tgt) {}
    }
    __syncthreads();                                           // B3
    __builtin_amdgcn_fence(__ATOMIC_ACQUIRE, "agent");

    // all-gather: 1024 chunks -> hbuf in A-fragment layout
    #pragma unroll
    for (int n = tid; n < 1024; n += 512) {
      const int p = n >> 7, rem = n & 127, r = rem >> 3, m = rem & 7;
      const ull v = __hip_atomic_load(&xg[(slot * 8 + p) * 128 + rem],
                                      __ATOMIC_RELAXED, __HIP_MEMORY_SCOPE_AGENT);
      // k0 = 32p + 4m -> s=p, g=m>>1, jj=(m&1)*4
      *reinterpret_cast<ull*>(
          &hbuf[((p * 4 + (m >> 1)) * 16 + r) * 8 + (m & 1) * 4]) = v;
    }
    ++tgt;
    __syncthreads();                                           // B4
  }
}

extern "C" void kernel_launch(void* const* d_in, const int* in_sizes, int n_in,
                              void* d_out, int out_size, void* d_ws, size_t ws_size,
                              hipStream_t stream) {
  const int*   tokens = (const int*)d_in[0];
  const float* emb    = (const float*)d_in[1];
  const float* W      = (const float*)d_in[2];
  const float* b      = (const float*)d_in[3];
  float* out = (float*)d_out;

  float*          zxs   = (float*)d_ws;                                  // 512 KB
  unsigned short* Wb    = (unsigned short*)((char*)d_ws + 512 * 1024);   // 512 KB
  ull*            xbuf  = (ull*)((char*)d_ws + 1024 * 1024);             // 256 KB
  unsigned int*   flags = (unsigned int*)((char*)d_ws + 1280 * 1024);    // 512 B

  lstm_prep<<<256, 256, 0, stream>>>(emb, W, b, zxs, Wb, flags);
  lstm_seq<<<128, 512, 0, stream>>>(tokens, zxs, Wb, xbuf, flags, out);
}